// Round 2
// baseline (846.838 us; speedup 1.0000x reference)
//
#include <hip/hip_runtime.h>

// SAGEConv: out = x@W_self + b_self + (mean_{u->v} x[u])@W_neigh + b_neigh
// N=50000, E=800000, D=O=64. ALL FP32 (per reference), int32 indices.
// Workspace: agg[N*64] fp32, then deg[N] fp32  (13.0 MB total).

// ---------------------------------------------------------------------------
// Phase 0: zero agg + deg (ws is poisoned 0xAA before every launch).
// ---------------------------------------------------------------------------
__global__ __launch_bounds__(256) void zero_ws(float4* __restrict__ ws, int n4) {
    int i = blockIdx.x * 256 + threadIdx.x;
    if (i < n4) ws[i] = float4{0.0f, 0.0f, 0.0f, 0.0f};
}

// ---------------------------------------------------------------------------
// Phase 1: edge scatter. 16 lanes per edge, each lane handles 4 features
// via one float4 load + 4 fp32 HW atomics.
// ---------------------------------------------------------------------------
__global__ __launch_bounds__(256) void sage_scatter(
    const float* __restrict__ x,
    const int* __restrict__ src,
    const int* __restrict__ dst,
    float* __restrict__ agg,
    float* __restrict__ deg,
    int E)
{
    long long t = (long long)blockIdx.x * 256 + threadIdx.x;
    int e = (int)(t >> 4);         // 16 lanes per edge
    if (e >= E) return;
    int lane = (int)(t & 15);

    int s = src[e];
    int d = dst[e];

    float4 v = reinterpret_cast<const float4*>(x + (size_t)s * 64)[lane];
    float* a = agg + (size_t)d * 64 + lane * 4;
    unsafeAtomicAdd(a + 0, v.x);
    unsafeAtomicAdd(a + 1, v.y);
    unsafeAtomicAdd(a + 2, v.z);
    unsafeAtomicAdd(a + 3, v.w);
    if (lane == 0) {
        unsafeAtomicAdd(&deg[d], 1.0f);
    }
}

// ---------------------------------------------------------------------------
// Phase 2: per-node transform. 4 nodes per 256-thread block; W in LDS.
// Lane o reads sW[d][o] (stride-1) and sx[nl][d] (broadcast) — conflict-free.
// ---------------------------------------------------------------------------
__global__ __launch_bounds__(256) void sage_out(
    const float* __restrict__ x,
    const float* __restrict__ agg,
    const float* __restrict__ deg,
    const float* __restrict__ Wself,
    const float* __restrict__ bself,
    const float* __restrict__ Wneigh,
    const float* __restrict__ bneigh,
    float* __restrict__ out,
    int N)
{
    __shared__ float sWs[64][64];
    __shared__ float sWn[64][64];
    __shared__ float sx[4][64];
    __shared__ float sh[4][64];

    int t = threadIdx.x;
    // Stage both 64x64 weight matrices into LDS (16 elems/thread each).
    for (int i = t; i < 64 * 64; i += 256) {
        sWs[i >> 6][i & 63] = Wself[i];
        sWn[i >> 6][i & 63] = Wneigh[i];
    }

    int o  = t & 63;
    int nl = t >> 6;
    int node = blockIdx.x * 4 + nl;

    float bias = bself[o] + bneigh[o];

    if (node < N) {
        sx[nl][o] = x[(size_t)node * 64 + o];
        float dv = deg[node];
        float inv = 1.0f / fmaxf(dv, 1.0f);
        sh[nl][o] = agg[(size_t)node * 64 + o] * inv;
    }
    __syncthreads();

    if (node >= N) return;

    float acc = bias;
#pragma unroll
    for (int d = 0; d < 64; ++d) {
        acc += sx[nl][d] * sWs[d][o] + sh[nl][d] * sWn[d][o];
    }
    out[(size_t)node * 64 + o] = acc;
}

// ---------------------------------------------------------------------------
extern "C" void kernel_launch(void* const* d_in, const int* in_sizes, int n_in,
                              void* d_out, int out_size, void* d_ws, size_t ws_size,
                              hipStream_t stream) {
    const float* x      = (const float*)d_in[0];
    const int*   src    = (const int*)d_in[1];
    const int*   dst    = (const int*)d_in[2];
    const float* Wself  = (const float*)d_in[3];
    const float* bself  = (const float*)d_in[4];
    const float* Wneigh = (const float*)d_in[5];
    const float* bneigh = (const float*)d_in[6];
    float* out = (float*)d_out;

    int N = in_sizes[0] / 64;
    int E = in_sizes[1];

    float* agg = (float*)d_ws;
    float* deg = agg + (size_t)N * 64;

    // Zero agg + deg. N*65 floats; N=50000 -> 3,250,000 floats -> 812,500 float4.
    int nfloats = N * 65;
    int n4 = nfloats / 4;
    zero_ws<<<(n4 + 255) / 256, 256, 0, stream>>>((float4*)d_ws, n4);
    // Handle any remainder (none for N=50000, but be safe).
    // (nfloats % 4 == 0 when N % 4 == 0; N=50000 is divisible by 4.)

    // Scatter: 16 lanes per edge.
    long long total = (long long)E * 16;
    int blocks = (int)((total + 255) / 256);
    sage_scatter<<<blocks, 256, 0, stream>>>(x, src, dst, agg, deg, E);

    // Transform: 4 nodes per block.
    sage_out<<<(N + 3) / 4, 256, 0, stream>>>(x, agg, deg, Wself, bself, Wneigh, bneigh, out, N);
}

// Round 3
// 308.566 us; speedup vs baseline: 2.7444x; 2.7444x over previous
//
#include <hip/hip_runtime.h>

// SAGEConv: out = x@W_self + b_self + (mean_{u->v} x[u])@W_neigh + b_neigh
// N=50000, E=800000, D=O=64. ALL FP32, int32 indices.
//
// Strategy: NO fp atomics. Build CSR by counting sort (deg histogram ->
// hierarchical exclusive scan -> cursor fill), then wave-per-node gather
// with the dense transform fused (weights in LDS).
//
// Workspace (ints): [deg N][cursor N][row_start N+1][bsum 256][boff 256][csr E]

// ---------------------------------------------------------------------------
__global__ __launch_bounds__(256) void zero_int(int* __restrict__ p, int n) {
    int i = blockIdx.x * 256 + threadIdx.x;
    if (i < n) p[i] = 0;
}

// Phase 1: degree histogram (int atomics, 800K ops).
__global__ __launch_bounds__(256) void count_deg(
    const int* __restrict__ dst, int* __restrict__ deg, int E)
{
    int e = blockIdx.x * 256 + threadIdx.x;
    if (e < E) atomicAdd(&deg[dst[e]], 1);
}

// Phase 2a: per-block inclusive scan (Hillis-Steele) -> block-local exclusive
// prefix in row_start, block total in bsum.
__global__ __launch_bounds__(256) void scan_blocks(
    const int* __restrict__ deg, int* __restrict__ row_start,
    int* __restrict__ bsum, int N)
{
    __shared__ int tmp[256];
    int t = threadIdx.x;
    int i = blockIdx.x * 256 + t;
    int v = (i < N) ? deg[i] : 0;
    tmp[t] = v;
    __syncthreads();
#pragma unroll
    for (int off = 1; off < 256; off <<= 1) {
        int a = (t >= off) ? tmp[t - off] : 0;
        __syncthreads();
        tmp[t] += a;
        __syncthreads();
    }
    if (i < N) row_start[i] = tmp[t] - v;   // exclusive, block-local
    if (t == 255) bsum[blockIdx.x] = tmp[255];
}

// Phase 2b: single-block exclusive scan of block sums (nb <= 256).
__global__ __launch_bounds__(256) void scan_partials(
    const int* __restrict__ bsum, int* __restrict__ boff, int nb)
{
    __shared__ int tmp[256];
    int t = threadIdx.x;
    int v = (t < nb) ? bsum[t] : 0;
    tmp[t] = v;
    __syncthreads();
#pragma unroll
    for (int off = 1; off < 256; off <<= 1) {
        int a = (t >= off) ? tmp[t - off] : 0;
        __syncthreads();
        tmp[t] += a;
        __syncthreads();
    }
    boff[t] = tmp[t] - v;   // exclusive
}

// Phase 2c: add block offsets; set row_start[N] = E.
__global__ __launch_bounds__(256) void scan_add(
    int* __restrict__ row_start, const int* __restrict__ boff, int N, int E)
{
    int i = blockIdx.x * 256 + threadIdx.x;
    if (i < N) row_start[i] += boff[blockIdx.x];
    if (i == 0) row_start[N] = E;
}

// Phase 3: fill CSR adjacency (int atomics on cursors).
__global__ __launch_bounds__(256) void fill_csr(
    const int* __restrict__ src, const int* __restrict__ dst,
    const int* __restrict__ row_start, int* __restrict__ cursor,
    int* __restrict__ csr, int E)
{
    int e = blockIdx.x * 256 + threadIdx.x;
    if (e >= E) return;
    int d = dst[e];
    int pos = atomicAdd(&cursor[d], 1);
    csr[row_start[d] + pos] = src[e];
}

// ---------------------------------------------------------------------------
// Phase 4: fused gather + transform. One wave per node (lane = feature).
// Edge loop: uniform u per wave -> one coalesced 256B read per edge.
// Transform: W in LDS; sx/sh are per-wave rows (intra-wave LDS ordering,
// no cross-wave hazard -> no barrier in the loop).
// ---------------------------------------------------------------------------
__global__ __launch_bounds__(256) void sage_gather_out(
    const float* __restrict__ x,
    const int* __restrict__ csr,
    const int* __restrict__ row_start,
    const float* __restrict__ Wself,
    const float* __restrict__ bself,
    const float* __restrict__ Wneigh,
    const float* __restrict__ bneigh,
    float* __restrict__ out,
    int N)
{
    __shared__ float sWs[64][64];
    __shared__ float sWn[64][64];
    __shared__ float sx[4][64];
    __shared__ float sh[4][64];

    int t = threadIdx.x;
    for (int i = t; i < 64 * 64; i += 256) {
        sWs[i >> 6][i & 63] = Wself[i];
        sWn[i >> 6][i & 63] = Wneigh[i];
    }
    __syncthreads();

    int lane = t & 63;
    int w    = t >> 6;
    float bias = bself[lane] + bneigh[lane];

    for (int v = blockIdx.x * 4 + w; v < N; v += gridDim.x * 4) {
        int beg = row_start[v];
        int end = row_start[v + 1];

        float acc = 0.0f;
        int k = beg;
        for (; k + 1 < end; k += 2) {
            int u0 = csr[k];
            int u1 = csr[k + 1];
            acc += x[(size_t)u0 * 64 + lane];
            acc += x[(size_t)u1 * 64 + lane];
        }
        if (k < end) acc += x[(size_t)csr[k] * 64 + lane];

        float degf = (float)(end - beg);
        float h = acc / fmaxf(degf, 1.0f);
        float xv = x[(size_t)v * 64 + lane];

        sx[w][lane] = xv;
        sh[w][lane] = h;
        // intra-wave LDS write->read: in-order DS pipe, no barrier needed

        float o = bias;
#pragma unroll
        for (int d = 0; d < 64; ++d) {
            o += sx[w][d] * sWs[d][lane] + sh[w][d] * sWn[d][lane];
        }
        out[(size_t)v * 64 + lane] = o;
    }
}

// ---------------------------------------------------------------------------
extern "C" void kernel_launch(void* const* d_in, const int* in_sizes, int n_in,
                              void* d_out, int out_size, void* d_ws, size_t ws_size,
                              hipStream_t stream) {
    const float* x      = (const float*)d_in[0];
    const int*   src    = (const int*)d_in[1];
    const int*   dst    = (const int*)d_in[2];
    const float* Wself  = (const float*)d_in[3];
    const float* bself  = (const float*)d_in[4];
    const float* Wneigh = (const float*)d_in[5];
    const float* bneigh = (const float*)d_in[6];
    float* out = (float*)d_out;

    int N = in_sizes[0] / 64;
    int E = in_sizes[1];

    int* deg       = (int*)d_ws;
    int* cursor    = deg + N;
    int* row_start = cursor + N;          // N+1
    int* bsum      = row_start + N + 1;   // 256
    int* boff      = bsum + 256;          // 256
    int* csr       = boff + 256;          // E

    int nb = (N + 255) / 256;             // <= 256 for N <= 65536

    // Zero deg + cursor (contiguous 2N ints).
    zero_int<<<(2 * N + 255) / 256, 256, 0, stream>>>(deg, 2 * N);

    count_deg<<<(E + 255) / 256, 256, 0, stream>>>(dst, deg, E);

    scan_blocks<<<nb, 256, 0, stream>>>(deg, row_start, bsum, N);
    scan_partials<<<1, 256, 0, stream>>>(bsum, boff, nb);
    scan_add<<<nb, 256, 0, stream>>>(row_start, boff, N, E);

    fill_csr<<<(E + 255) / 256, 256, 0, stream>>>(src, dst, row_start, cursor, csr, E);

    // 1024 blocks = 4 blocks/CU (LDS 34KB/block -> 4 blocks fit in 160KB).
    sage_gather_out<<<1024, 256, 0, stream>>>(x, csr, row_start,
                                              Wself, bself, Wneigh, bneigh, out, N);
}

// Round 4
// 223.504 us; speedup vs baseline: 3.7889x; 1.3806x over previous
//
#include <hip/hip_runtime.h>

// SAGEConv: out = x@W_self + b_self + (mean_{u->v} x[u])@W_neigh + b_neigh
// N=50000, E=800000, D=O=64. FP32 in/out, int32 indices.
//
// CSR build (histogram -> hierarchical scan -> countdown fill), then fused
// wave-per-4-nodes gather (readlane-uniform edge loop, 4 accumulators) +
// transform with bf16-packed pairs in LDS (1 ds_read per W-pair / in-pair).
//
// Workspace (ints): [deg N][row_start N+1][bsum 256][boff 256][csr E]

__device__ __forceinline__ unsigned pack_bf2(float a, float b) {
    unsigned ua = __builtin_bit_cast(unsigned, a);
    unsigned ub = __builtin_bit_cast(unsigned, b);
    ua += 0x7fffu + ((ua >> 16) & 1u);   // RNE round to bf16
    ub += 0x7fffu + ((ub >> 16) & 1u);
    return (ua >> 16) | (ub & 0xffff0000u);
}

// ---------------------------------------------------------------------------
__global__ __launch_bounds__(256) void zero_int(int* __restrict__ p, int n) {
    int i = blockIdx.x * 256 + threadIdx.x;
    if (i < n) p[i] = 0;
}

__global__ __launch_bounds__(256) void count_deg(
    const int* __restrict__ dst, int* __restrict__ deg, int E)
{
    int e = blockIdx.x * 256 + threadIdx.x;
    if (e < E) atomicAdd(&deg[dst[e]], 1);
}

__global__ __launch_bounds__(256) void scan_blocks(
    const int* __restrict__ deg, int* __restrict__ row_start,
    int* __restrict__ bsum, int N)
{
    __shared__ int tmp[256];
    int t = threadIdx.x;
    int i = blockIdx.x * 256 + t;
    int v = (i < N) ? deg[i] : 0;
    tmp[t] = v;
    __syncthreads();
#pragma unroll
    for (int off = 1; off < 256; off <<= 1) {
        int a = (t >= off) ? tmp[t - off] : 0;
        __syncthreads();
        tmp[t] += a;
        __syncthreads();
    }
    if (i < N) row_start[i] = tmp[t] - v;
    if (t == 255) bsum[blockIdx.x] = tmp[255];
}

__global__ __launch_bounds__(256) void scan_partials(
    const int* __restrict__ bsum, int* __restrict__ boff, int nb)
{
    __shared__ int tmp[256];
    int t = threadIdx.x;
    int v = (t < nb) ? bsum[t] : 0;
    tmp[t] = v;
    __syncthreads();
#pragma unroll
    for (int off = 1; off < 256; off <<= 1) {
        int a = (t >= off) ? tmp[t - off] : 0;
        __syncthreads();
        tmp[t] += a;
        __syncthreads();
    }
    boff[t] = tmp[t] - v;
}

__global__ __launch_bounds__(256) void scan_add(
    int* __restrict__ row_start, const int* __restrict__ boff, int N, int E)
{
    int i = blockIdx.x * 256 + threadIdx.x;
    if (i < N) row_start[i] += boff[blockIdx.x];
    if (i == 0) row_start[N] = E;
}

// Countdown fill: reuses deg as cursor (edge order within a bucket is free).
__global__ __launch_bounds__(256) void fill_csr(
    const int* __restrict__ src, const int* __restrict__ dst,
    const int* __restrict__ row_start, int* __restrict__ deg,
    int* __restrict__ csr, int E)
{
    int e = blockIdx.x * 256 + threadIdx.x;
    if (e >= E) return;
    int d = dst[e];
    int pos = atomicAdd(&deg[d], -1) - 1;
    csr[row_start[d] + pos] = src[e];
}

// ---------------------------------------------------------------------------
// Fused gather + transform. Block = 4 waves; wave owns 4 nodes.
// Gather: adjacency loaded once coalesced (csr[beg+lane]); edges iterated via
// v_readlane (uniform u -> scalar-base row loads), 4 independent accumulators.
// Transform: LDS words hold bf16 pairs; per d: 1 W-pair read (stride-1) +
// 1 in-pair broadcast read per node (amortized over 4 nodes).
// ---------------------------------------------------------------------------
__global__ __launch_bounds__(256) void sage_gather_out(
    const float* __restrict__ x,
    const int* __restrict__ csr,
    const int* __restrict__ row_start,
    const float* __restrict__ Wself,
    const float* __restrict__ bself,
    const float* __restrict__ Wneigh,
    const float* __restrict__ bneigh,
    float* __restrict__ out,
    int N, int E)
{
    __shared__ unsigned sW[64 * 64];    // pack(Ws[d][o], Wn[d][o])
    __shared__ unsigned sIn[16 * 64];   // pack(x[v][o], h[v][o])

    int t = threadIdx.x;
    for (int i = t; i < 64 * 64; i += 256) {
        sW[i] = pack_bf2(Wself[i], Wneigh[i]);
    }
    __syncthreads();

    int lane = t & 63;
    int w    = t >> 6;
    float bias = bself[lane] + bneigh[lane];

    int vbase = blockIdx.x * 16 + w * 4;

    // ---- gather phase: 4 nodes sequentially, deep-unrolled edge loop ----
    for (int n = 0; n < 4; ++n) {
        int v = vbase + n;
        if (v >= N) break;
        int beg = row_start[v];
        int end = row_start[v + 1];
        int deg = end - beg;

        float a0 = 0.f, a1 = 0.f, a2 = 0.f, a3 = 0.f;
        for (int c = 0; c < deg; c += 64) {
            int idx = beg + c + lane;
            int cs = csr[idx < E ? idx : E - 1];
            int cnt = min(deg - c, 64);
            int j = 0;
            for (; j + 3 < cnt; j += 4) {
                int u0 = __builtin_amdgcn_readlane(cs, j);
                int u1 = __builtin_amdgcn_readlane(cs, j + 1);
                int u2 = __builtin_amdgcn_readlane(cs, j + 2);
                int u3 = __builtin_amdgcn_readlane(cs, j + 3);
                a0 += x[(size_t)u0 * 64 + lane];
                a1 += x[(size_t)u1 * 64 + lane];
                a2 += x[(size_t)u2 * 64 + lane];
                a3 += x[(size_t)u3 * 64 + lane];
            }
            for (; j < cnt; ++j) {
                int u0 = __builtin_amdgcn_readlane(cs, j);
                a0 += x[(size_t)u0 * 64 + lane];
            }
        }
        float h  = ((a0 + a1) + (a2 + a3)) / fmaxf((float)deg, 1.0f);
        float xv = x[(size_t)v * 64 + lane];
        sIn[(w * 4 + n) * 64 + lane] = pack_bf2(xv, h);
        // intra-wave LDS write->read ordering (in-order DS pipe): no barrier
    }

    // ---- transform phase ----
    float acc0 = bias, acc1 = bias, acc2 = bias, acc3 = bias;
#pragma unroll 16
    for (int d = 0; d < 64; ++d) {
        unsigned wv = sW[d * 64 + lane];
        float ws = __builtin_bit_cast(float, wv << 16);
        float wn = __builtin_bit_cast(float, wv & 0xffff0000u);

        unsigned i0 = sIn[(w * 4 + 0) * 64 + d];
        unsigned i1 = sIn[(w * 4 + 1) * 64 + d];
        unsigned i2 = sIn[(w * 4 + 2) * 64 + d];
        unsigned i3 = sIn[(w * 4 + 3) * 64 + d];

        acc0 += __builtin_bit_cast(float, i0 << 16) * ws
              + __builtin_bit_cast(float, i0 & 0xffff0000u) * wn;
        acc1 += __builtin_bit_cast(float, i1 << 16) * ws
              + __builtin_bit_cast(float, i1 & 0xffff0000u) * wn;
        acc2 += __builtin_bit_cast(float, i2 << 16) * ws
              + __builtin_bit_cast(float, i2 & 0xffff0000u) * wn;
        acc3 += __builtin_bit_cast(float, i3 << 16) * ws
              + __builtin_bit_cast(float, i3 & 0xffff0000u) * wn;
    }

    float accs[4] = {acc0, acc1, acc2, acc3};
    for (int n = 0; n < 4; ++n) {
        int v = vbase + n;
        if (v < N) out[(size_t)v * 64 + lane] = accs[n];
    }
}

// ---------------------------------------------------------------------------
extern "C" void kernel_launch(void* const* d_in, const int* in_sizes, int n_in,
                              void* d_out, int out_size, void* d_ws, size_t ws_size,
                              hipStream_t stream) {
    const float* x      = (const float*)d_in[0];
    const int*   src    = (const int*)d_in[1];
    const int*   dst    = (const int*)d_in[2];
    const float* Wself  = (const float*)d_in[3];
    const float* bself  = (const float*)d_in[4];
    const float* Wneigh = (const float*)d_in[5];
    const float* bneigh = (const float*)d_in[6];
    float* out = (float*)d_out;

    int N = in_sizes[0] / 64;
    int E = in_sizes[1];

    int* deg       = (int*)d_ws;
    int* row_start = deg + N;             // N+1
    int* bsum      = row_start + N + 1;   // 256
    int* boff      = bsum + 256;          // 256
    int* csr       = boff + 256;          // E

    int nb = (N + 255) / 256;             // 196 <= 256

    zero_int<<<(N + 255) / 256, 256, 0, stream>>>(deg, N);
    count_deg<<<(E + 255) / 256, 256, 0, stream>>>(dst, deg, E);
    scan_blocks<<<nb, 256, 0, stream>>>(deg, row_start, bsum, N);
    scan_partials<<<1, 256, 0, stream>>>(bsum, boff, nb);
    scan_add<<<nb, 256, 0, stream>>>(row_start, boff, N, E);
    fill_csr<<<(E + 255) / 256, 256, 0, stream>>>(src, dst, row_start, deg, csr, E);

    sage_gather_out<<<(N + 15) / 16, 256, 0, stream>>>(
        x, csr, row_start, Wself, bself, Wneigh, bneigh, out, N, E);
}